// Round 5
// baseline (552.212 us; speedup 1.0000x reference)
//
#include <hip/hip_runtime.h>

#define EDGES    800000
#define IN_F     64
#define HID      128
#define TPB      512               // 8 waves per WG, persistent
#define GRID     256               // 1 WG per CU (LDS-capped anyway)
#define EPT      256               // edges per WG-tile (32 per wave)
#define NTILES   (EDGES / EPT)     // 3125

typedef _Float16 half8  __attribute__((ext_vector_type(8)));
typedef _Float16 half4  __attribute__((ext_vector_type(4)));
typedef __fp16   fp16x2 __attribute__((ext_vector_type(2)));
typedef float    f32x4  __attribute__((ext_vector_type(4)));

__device__ __forceinline__ float fast_tanh(float x) {
    float e = __builtin_amdgcn_exp2f(2.8853900817779268f * x);   // e^{2x}
    return 1.0f - 2.0f * __builtin_amdgcn_rcpf(e + 1.0f);
}
__device__ __forceinline__ float fast_sigmoid(float x) {
    return __builtin_amdgcn_rcpf(1.0f + __builtin_amdgcn_exp2f(-1.4426950408889634f * x));
}
__device__ __forceinline__ half4 tanh_pack4(f32x4 a) {
    fp16x2 lo = __builtin_amdgcn_cvt_pkrtz(fast_tanh(a[0]), fast_tanh(a[1]));
    fp16x2 hi = __builtin_amdgcn_cvt_pkrtz(fast_tanh(a[2]), fast_tanh(a[3]));
    half4 r;
    r[0] = (_Float16)lo[0]; r[1] = (_Float16)lo[1];
    r[2] = (_Float16)hi[0]; r[3] = (_Float16)hi[1];
    return r;
}
__device__ __forceinline__ half8 pack8(float4 a, float4 b) {
    fp16x2 p0 = __builtin_amdgcn_cvt_pkrtz(a.x, a.y);
    fp16x2 p1 = __builtin_amdgcn_cvt_pkrtz(a.z, a.w);
    fp16x2 p2 = __builtin_amdgcn_cvt_pkrtz(b.x, b.y);
    fp16x2 p3 = __builtin_amdgcn_cvt_pkrtz(b.z, b.w);
    half8 h;
    h[0]=(_Float16)p0[0]; h[1]=(_Float16)p0[1]; h[2]=(_Float16)p1[0]; h[3]=(_Float16)p1[1];
    h[4]=(_Float16)p2[0]; h[5]=(_Float16)p2[1]; h[6]=(_Float16)p3[0]; h[7]=(_Float16)p3[1];
    return h;
}

#define MFMA(a, b, c) __builtin_amdgcn_mfma_f32_16x16x32_f16((a), (b), (c), 0, 0, 0)

// LDS map (bytes): [0,81920) weights f16 (W1 8192h | W2 @8192h | W3 @24576h),
// [81920,83968) biases f32 (b1|b2|b3|w4, 128 each), [83968,149504) H tiles
// (8 waves x 32 edges x 128 halfs). All f16 regions XOR-swizzled on 8-half
// blocks: blk' = blk ^ (row & 7)  -> b128 reads land 2-way max (free, m136).
#define LDS_BYTES 149504
#define LW2_OFF   8192            // halfs
#define LW3_OFF   24576
#define LH_OFF    83968           // bytes

struct EdgeBuf { float4 v[8]; };   // [s*4 + t*2 + h]

__device__ __forceinline__ void load_edges(EdgeBuf& d, const float* __restrict__ ea,
                                           int T, int w, int l16, int q) {
    const float* base = ea + (long)(T * EPT + w * 32 + l16) * IN_F + q * 8;
    #pragma unroll
    for (int s = 0; s < 2; ++s)
        #pragma unroll
        for (int t = 0; t < 2; ++t) {
            const float* p = base + s * 16 * IN_F + t * 32;
            d.v[s * 4 + t * 2]     = *(const float4*)p;
            d.v[s * 4 + t * 2 + 1] = *(const float4*)(p + 4);
        }
}

__device__ __forceinline__ void compute_tile(const EdgeBuf& eb, _Float16* LW,
                                             const float* BS, _Float16* Hw,
                                             int l16, int q, int sw,
                                             float* __restrict__ out, int obase,
                                             int lane, float bb) {
    const int wq = q >> 1, wo = (q & 1) * 4;
    half8 bf[2][4];

    // ---- Layer 1 (K=64) ----
    bf[0][0] = pack8(eb.v[0], eb.v[1]);  bf[0][1] = pack8(eb.v[2], eb.v[3]);
    bf[1][0] = pack8(eb.v[4], eb.v[5]);  bf[1][1] = pack8(eb.v[6], eb.v[7]);
    #pragma unroll
    for (int it = 0; it < 8; ++it) {
        float4 bv = *(const float4*)&BS[it * 16 + q * 4];
        f32x4 a0, a1;
        a0[0]=bv.x; a0[1]=bv.y; a0[2]=bv.z; a0[3]=bv.w;  a1 = a0;
        #pragma unroll
        for (int t = 0; t < 2; ++t) {
            half8 af = *(const half8*)&LW[(it * 16 + l16) * IN_F + (((t * 4 + q) ^ sw) << 3)];
            a0 = MFMA(af, bf[0][t], a0);
            a1 = MFMA(af, bf[1][t], a1);
        }
        const int blk = ((2 * it + wq) ^ sw) << 3;
        *(half4*)&Hw[l16 * HID + blk + wo]        = tanh_pack4(a0);
        *(half4*)&Hw[(16 + l16) * HID + blk + wo] = tanh_pack4(a1);
    }

    // ---- Layer 2 (K=128) ----
    #pragma unroll
    for (int s = 0; s < 2; ++s)
        #pragma unroll
        for (int t = 0; t < 4; ++t)
            bf[s][t] = *(const half8*)&Hw[(s * 16 + l16) * HID + (((t * 4 + q) ^ sw) << 3)];
    #pragma unroll
    for (int it = 0; it < 8; ++it) {
        float4 bv = *(const float4*)&BS[128 + it * 16 + q * 4];
        f32x4 a0, a1;
        a0[0]=bv.x; a0[1]=bv.y; a0[2]=bv.z; a0[3]=bv.w;  a1 = a0;
        #pragma unroll
        for (int t = 0; t < 4; ++t) {
            half8 af = *(const half8*)&LW[LW2_OFF + (it * 16 + l16) * HID + (((t * 4 + q) ^ sw) << 3)];
            a0 = MFMA(af, bf[0][t], a0);
            a1 = MFMA(af, bf[1][t], a1);
        }
        const int blk = ((2 * it + wq) ^ sw) << 3;
        *(half4*)&Hw[l16 * HID + blk + wo]        = tanh_pack4(a0);
        *(half4*)&Hw[(16 + l16) * HID + blk + wo] = tanh_pack4(a1);
    }

    // ---- Layer 3 + fused layer-4 dot ----
    #pragma unroll
    for (int s = 0; s < 2; ++s)
        #pragma unroll
        for (int t = 0; t < 4; ++t)
            bf[s][t] = *(const half8*)&Hw[(s * 16 + l16) * HID + (((t * 4 + q) ^ sw) << 3)];
    float p0 = 0.0f, p1 = 0.0f;
    #pragma unroll
    for (int it = 0; it < 8; ++it) {
        float4 bv = *(const float4*)&BS[256 + it * 16 + q * 4];
        float4 wv = *(const float4*)&BS[384 + it * 16 + q * 4];
        f32x4 a0, a1;
        a0[0]=bv.x; a0[1]=bv.y; a0[2]=bv.z; a0[3]=bv.w;  a1 = a0;
        #pragma unroll
        for (int t = 0; t < 4; ++t) {
            half8 af = *(const half8*)&LW[LW3_OFF + (it * 16 + l16) * HID + (((t * 4 + q) ^ sw) << 3)];
            a0 = MFMA(af, bf[0][t], a0);
            a1 = MFMA(af, bf[1][t], a1);
        }
        p0 += fast_tanh(a0[0]) * wv.x + fast_tanh(a0[1]) * wv.y
            + fast_tanh(a0[2]) * wv.z + fast_tanh(a0[3]) * wv.w;
        p1 += fast_tanh(a1[0]) * wv.x + fast_tanh(a1[1]) * wv.y
            + fast_tanh(a1[2]) * wv.z + fast_tanh(a1[3]) * wv.w;
    }
    p0 += __shfl_xor(p0, 16, 64);  p0 += __shfl_xor(p0, 32, 64);
    p1 += __shfl_xor(p1, 16, 64);  p1 += __shfl_xor(p1, 32, 64);
    if (lane < 16)      out[obase + lane] = fast_sigmoid(p0 + bb);
    else if (lane < 32) out[obase + lane] = fast_sigmoid(p1 + bb);
}

__global__ __launch_bounds__(TPB, 2)
void mlp_persistent(const float* __restrict__ ea,
                    const float* __restrict__ W1, const float* __restrict__ b1,
                    const float* __restrict__ W2, const float* __restrict__ b2,
                    const float* __restrict__ W3, const float* __restrict__ b3,
                    const float* __restrict__ w4, const float* __restrict__ b4,
                    float* __restrict__ out) {
    __shared__ __align__(16) unsigned char SMEM[LDS_BYTES];
    _Float16* LW = (_Float16*)SMEM;
    float*    BS = (float*)(SMEM + 81920);
    _Float16* LH = (_Float16*)(SMEM + LH_OFF);

    const int tid  = threadIdx.x;
    const int w    = tid >> 6;
    const int lane = tid & 63;
    const int l16  = lane & 15;
    const int q    = lane >> 4;
    const int sw   = l16 & 7;
    _Float16* Hw = LH + w * (32 * HID);

    // ---- One-time: stage weights (f16, swizzled) + biases into LDS ----
    #pragma unroll 2
    for (int b = tid; b < 1024; b += TPB) {          // W1: 128 x 8 blocks
        int r = b >> 3, c = b & 7;
        const float* g = W1 + r * IN_F + c * 8;
        *(half8*)&LW[r * IN_F + ((c ^ (r & 7)) << 3)] =
            pack8(*(const float4*)g, *(const float4*)(g + 4));
    }
    #pragma unroll 4
    for (int b = tid; b < 2048; b += TPB) {          // W2: 128 x 16 blocks
        int r = b >> 4, c = b & 15;
        const float* g = W2 + r * HID + c * 8;
        *(half8*)&LW[LW2_OFF + r * HID + ((c ^ (r & 7)) << 3)] =
            pack8(*(const float4*)g, *(const float4*)(g + 4));
    }
    #pragma unroll 4
    for (int b = tid; b < 2048; b += TPB) {          // W3
        int r = b >> 4, c = b & 15;
        const float* g = W3 + r * HID + c * 8;
        *(half8*)&LW[LW3_OFF + r * HID + ((c ^ (r & 7)) << 3)] =
            pack8(*(const float4*)g, *(const float4*)(g + 4));
    }
    if (tid < 128)      BS[tid]       = b1[tid];
    else if (tid < 256) BS[tid]       = b2[tid - 128];
    else if (tid < 384) BS[tid]       = b3[tid - 256];
    else                BS[tid]       = w4[tid - 384];
    __syncthreads();
    const float bb = b4[0];

    // ---- Persistent grid-stride over tiles, parity-double-buffered ----
    EdgeBuf A, B;
    int T = blockIdx.x;
    load_edges(A, ea, T, w, l16, q);
    while (true) {
        int T2 = T + GRID;
        if (T2 < NTILES) load_edges(B, ea, T2, w, l16, q);
        compute_tile(A, LW, BS, Hw, l16, q, sw, out, T * EPT + w * 32, lane, bb);
        if (T2 >= NTILES) break;
        int T3 = T2 + GRID;
        if (T3 < NTILES) load_edges(A, ea, T3, w, l16, q);
        compute_tile(B, LW, BS, Hw, l16, q, sw, out, T2 * EPT + w * 32, lane, bb);
        if (T3 >= NTILES) break;
        T = T3;
    }
}

extern "C" void kernel_launch(void* const* d_in, const int* in_sizes, int n_in,
                              void* d_out, int out_size, void* d_ws, size_t ws_size,
                              hipStream_t stream) {
    // setup_inputs order: x, edge_index, edge_attr, W1,b1, W2,b2, W3,b3, W4,b4
    const float* ea = (const float*)d_in[2];
    const float* W1 = (const float*)d_in[3];
    const float* b1 = (const float*)d_in[4];
    const float* W2 = (const float*)d_in[5];
    const float* b2 = (const float*)d_in[6];
    const float* W3 = (const float*)d_in[7];
    const float* b3 = (const float*)d_in[8];
    const float* W4 = (const float*)d_in[9];
    const float* b4 = (const float*)d_in[10];
    float* out = (float*)d_out;

    hipLaunchKernelGGL(mlp_persistent, dim3(GRID), dim3(TPB), 0, stream,
                       ea, W1, b1, W2, b2, W3, b3, W4, b4, out);
}